// Round 6
// baseline (3859.534 us; speedup 1.0000x reference)
//
#include <hip/hip_runtime.h>

// WarpingLayer_3stacks: trilinear scatter-splat (grid_push) of
// intensities = [x*mask, mask] into 128^3, coords = flow + meshgrid.
// Input 384x128x128 f32. Output [1,2,128,128,128] f32.
//
// R1: global f32 atomicAdd is the wall -> privatize in LDS.
// R7/R8: pack both channels in one u64 (ds_add_u64, 32.18 fixed pt).
// R9: fuse gather+plane; R10: TZ=8 scan-amp cut -> 193.
// R11: 512g+256p = 768 blocks = 3/CU, {2g+1p}/CU. 190us, K1=75.6us. BEST.
// R12 FAILED (200): 4 blocks/CU doubled partials+overhead. Not occupancy.
// R13 FAILED (198): per-lane apron filter useless (cost is per-wave).
// R14 FAILED (304): symmetric HALO=2 record flood - driven by Y (sigma=1,
//     P=0.048/corner); 0.38 records/px swamped scnt + K2.
// R15 FAILED (221): 2 blocks/CU latency-bound; geometry bracketed:
//     2/CU=103, 3/CU=75.6, 4/CU=87. 3 blocks/CU frozen.
// R16 FAILED (203, K1 90): register prefetch pipeline displaced the
//     compiler schedule (+12 VGPR of copies); VALUBusy 49->41. ILP,
//     TLP, filtering, tile-size all refuted - R11 loop body is frozen.
// R17: ASYMMETRIC halo. flow_z is prescaled by 127/383=0.331 (sigma_z
//     ~0.33 vs sigma_y ~1.0), so the z-halo can be 1 where y needs 3:
//     NZ=1, NY=3 -> scan (8+2)x(4+6)=100 rows vs 140 (-29% gather
//     issue+fetch). Far-z corners (|fz|>3.02, P~0.0025/px) -> ~21K
//     records (mean 130/block, REG_CAP 1024 safe). Dead slots (12 of
//     112) load-clamped to row 99 (L1 hit, no dead HBM fetch). Loop
//     body/plane/K2 byte-identical to R11.

#define OS    128
#define OS3   (OS * OS * OS)
#define SRC_D 384
#define SRC_H 128
#define SRC_W 128
#define NSRC  (SRC_D * SRC_H * SRC_W)
#define ZSPLIT 128
#define PLANE_CELLS (OS * OS)

// gather tiling: block owns out[z0:z0+8][y0:y0+4][0:128]
#define TZ 8
#define TY 4
#define NZ 1               // z near/scan halo (flow_z prescaled by 0.331)
#define NY 3               // y near/scan halo
#define NJOBS 100          // (TZ+2*NZ)=10 z-rows x (TY+2*NY)=10 y-rows
#define GITER 7            // ceil(100/16)
#define GBLK  512          // 16 z-tiles x 32 y-tiles

// plane tiling: quarter-plane (32 rows) per block, 4 z-slabs per group
#define PGROUPS 64         // z-groups (4 slabs each)
#define PSPB    4
#define PBLK    (PGROUPS * 4)   // 256 plane blocks

#define REG_CAP 1024       // per-gather-block record region (mean ~130)
#define LCAP    65536      // shared overflow list

// ws layout (bytes)
#define OFF_CNT    0
#define OFF_COUNTS 1024
#define OFF_REGS   8192
#define OFF_LIST   (OFF_REGS + GBLK * REG_CAP * 16)           //  8,396,800
#define OFF_PART   (16 * 1024 * 1024)
#define WS_NEED    (OFF_PART + PGROUPS * 2 * PLANE_CELLS * 4) // 24 MB

#define S_FIX   262144.0f            // 2^18
#define INV_FIX (1.0f / 262144.0f)

// pack prescaled (a = v*wgt*2^18, b = m*wgt*2^18) via truncating cvt.
// b >= 0 and cell sums << 2^31 so low field never carries into high field.
__device__ __forceinline__ unsigned long long packt(float a, float b) {
    int vi = (int)a;
    int mi = (int)b;
    return ((unsigned long long)(unsigned)vi << 32) | (unsigned long long)(unsigned)mi;
}

// u64-cell bank swizzle (involution): spreads stride-4 column access.
__device__ __forceinline__ int swzq(int c) { return c ^ ((c >> 4) & 7); }

__device__ __forceinline__ void atomAddF(float* p, float v) {
    unsafeAtomicAdd(p, v);
}

// =================== K1: fused gather (z<128) + plane (z>=128) =============
// grid.x = GBLK + PBLK = 768, 512 threads, 32KB LDS -> exactly 3 blocks/CU;
// round-robin dispatch => each CU holds 2 gather + 1 plane (balanced atomics).
__global__ __launch_bounds__(512) void warp_fused(
    const float* __restrict__ x, const float* __restrict__ flow,
    const float* __restrict__ mask, float* __restrict__ out,
    float* __restrict__ partials,
    unsigned* __restrict__ gcnt, int* __restrict__ counts,
    int4* __restrict__ regs, int4* __restrict__ list)
{
    __shared__ unsigned long long sh[4096];   // 32 KB
    __shared__ int scnt;

    const int tid = threadIdx.x;
    const int b = blockIdx.x;

    const float4* __restrict__ fz4 = (const float4*)flow;
    const float4* __restrict__ fy4 = (const float4*)(flow + NSRC);
    const float4* __restrict__ fx4 = (const float4*)(flow + 2 * NSRC);
    const float4* __restrict__ m4p = (const float4*)mask;
    const float4* __restrict__ x4p = (const float4*)x;

    if (b < GBLK) {
        // ---------------- gather role ----------------
        if (tid == 0) scnt = 0;
        #pragma unroll
        for (int s = 0; s < 4096 / 512; ++s)
            sh[tid + s * 512] = 0ull;
        __syncthreads();

        const int z0 = (b & 15) * TZ;
        const int y0 = (b >> 4) * TY;
        const int wq = tid & 31;
        const int slot = tid >> 5;

        for (int it = 0; it < GITER; ++it) {
            int j = it * 16 + slot;
            int jj = min(j, NJOBS - 1);          // dead slots re-load row 99
            int dz = jj / 10, dyy = jj - dz * 10;
            int zzr = z0 - NZ + dz;
            int hhr = y0 - NY + dyy;
            int zz = min(max(zzr, 0), ZSPLIT - 1);
            int hh = min(max(hhr, 0), OS - 1);
            bool vrow = (j < NJOBS) && (zzr >= 0) && (zzr < ZSPLIT) &&
                        (hhr >= 0) && (hhr < OS);
            bool home = vrow && (zzr >= z0) && (zzr < z0 + TZ) &&
                        (hhr >= y0) && (hhr < y0 + TY);

            int idx4 = (((zz << 14) + (hh << 7)) >> 2) + wq;
            float4 vfz = fz4[idx4];       // unconditional clamped-address loads
            float4 vfy = fy4[idx4];
            float4 vfx = fx4[idx4];
            float4 vm  = m4p[idx4];
            float4 vx  = x4p[idx4];

            if (!vrow) continue;

            #pragma unroll
            for (int p = 0; p < 4; ++p) {
                float gz = ((float*)&vfz)[p] + (float)zz;
                float gy = ((float*)&vfy)[p] + (float)hh;
                float fzf = floorf(gz), fyf = floorf(gy);
                float ffz = gz - fzf, ffy = gy - fyf;
                int iz0 = (int)fzf, iy0 = (int)fyf;

                int cz0 = min(max(iz0,     0), OS - 1);
                int cz1 = min(max(iz0 + 1, 0), OS - 1);
                int cy0 = min(max(iy0,     0), OS - 1);
                int cy1 = min(max(iy0 + 1, 0), OS - 1);

                bool zin = (cz1 >= z0) && (cz0 < z0 + TZ);
                bool yin = (cy1 >= y0) && (cy0 < y0 + TY);
                if (!home && !(zin && yin)) continue;

                int w = wq * 4 + p;
                float gx = ((float*)&vfx)[p] + (float)w;
                float fxf = floorf(gx);
                float ffx = gx - fxf;
                int ix0 = (int)fxf;
                int cx0 = min(max(ix0,     0), OS - 1);
                int cx1 = min(max(ix0 + 1, 0), OS - 1);

                float m = ((float*)&vm)[p];
                float v = ((float*)&vx)[p] * m;
                float v_s = v * S_FIX;      // prescaled fixed-point inputs
                float m_s = m * S_FIX;

                #pragma unroll
                for (int d2 = 0; d2 < 2; ++d2) {
                    int cz = d2 ? cz1 : cz0;
                    float wz = d2 ? ffz : 1.0f - ffz;
                    bool nz = (cz - zz <= NZ) && (zz - cz <= NZ);
                    int uz = cz - z0;
                    #pragma unroll
                    for (int e2 = 0; e2 < 2; ++e2) {
                        int cy = e2 ? cy1 : cy0;
                        float wzy = wz * (e2 ? ffy : 1.0f - ffy);
                        bool ny = (cy - hh <= NY) && (hh - cy <= NY);
                        int uy = cy - y0;
                        bool nearc = nz && ny;
                        #pragma unroll
                        for (int f2 = 0; f2 < 2; ++f2) {
                            int cx = f2 ? cx1 : cx0;
                            float wgt = wzy * (f2 ? ffx : 1.0f - ffx);
                            if (nearc) {
                                if ((unsigned)uz < TZ && (unsigned)uy < TY) {
                                    int off = ((uz * TY + uy) << 7) + swzq(cx);
                                    atomicAdd(&sh[off], packt(v_s * wgt, m_s * wgt));
                                }
                            } else if (home) {
                                int4 r;
                                r.x = (cz << 14) + (cy << 7) + cx;
                                r.y = __float_as_int(v * wgt);
                                r.z = __float_as_int(m * wgt);
                                r.w = 0;
                                int s = atomicAdd(&scnt, 1);
                                if (s < REG_CAP) regs[b * REG_CAP + s] = r;
                                else {
                                    unsigned g = atomicAdd(gcnt, 1u);
                                    if (g < LCAP) list[g] = r;
                                }
                            }
                        }
                    }
                }
            }
        }

        __syncthreads();
        if (tid == 0) counts[b] = min(scnt, REG_CAP);

        // unpack + plain-store owned tile (tile grid partitions the volume)
        for (int i = tid; i < TZ * TY * OS; i += 512) {
            int row = i >> 7;              // uz*TY + uy, 0..31
            int c   = i & 127;
            unsigned long long cell = sh[(row << 7) | swzq(c)];
            float v = (float)(int)(cell >> 32) * INV_FIX;
            float m = (float)(int)(unsigned)cell * INV_FIX;
            int uz = row >> 2, uy = row & 3;
            int o = ((z0 + uz) << 14) + ((y0 + uy) << 7) + c;
            out[o]       = v;
            out[OS3 + o] = m;
        }
    } else {
        // ---------------- plane role: quarter-plane, 4 z-slabs (R11) -------
        const int pb = b - GBLK;
        const int g  = pb >> 2;           // z-group: slabs 128+4g .. 131+4g
        const int q  = pb & 3;            // y-quarter
        const int ybase = q << 5;
        const int rlo = max(0, ybase - 5);
        const int rhi = min(OS, ybase + 32 + 5);

        #pragma unroll
        for (int s = 0; s < 4096 / 512; ++s)
            sh[tid + s * 512] = 0ull;
        __syncthreads();

        const int wq = tid & 31;
        const int rs = tid >> 5;          // 0..15

        for (int s = 0; s < PSPB; ++s) {
            int z = ZSPLIT + g * PSPB + s;
            for (int rb = 0; rb < 3; ++rb) {
                int r = rlo + rb * 16 + rs;
                bool valid = r < rhi;
                int rc = min(r, OS - 1);
                int idx4 = (((z << 14) + (rc << 7)) >> 2) + wq;
                float4 vfz = fz4[idx4];
                float4 vfy = fy4[idx4];
                float4 vfx = fx4[idx4];
                float4 vm  = m4p[idx4];
                float4 vx  = x4p[idx4];
                if (!valid) continue;
                bool homeRow = ((r >> 5) == q);

                #pragma unroll
                for (int p = 0; p < 4; ++p) {
                    int w = wq * 4 + p;
                    float gz = ((float*)&vfz)[p] + (float)z;
                    float gy = ((float*)&vfy)[p] + (float)r;
                    float gx = ((float*)&vfx)[p] + (float)w;
                    float m  = ((float*)&vm)[p];
                    float v  = ((float*)&vx)[p] * m;

                    float fyf = floorf(gy), fxf = floorf(gx);
                    float ffy = gy - fyf, ffx = gx - fxf;
                    int iy0 = (int)fyf, ix0 = (int)fxf;
                    int cy0 = min(max(iy0,     0), OS - 1);
                    int cy1 = min(max(iy0 + 1, 0), OS - 1);
                    int cx0 = min(max(ix0,     0), OS - 1);
                    int cx1 = min(max(ix0 + 1, 0), OS - 1);
                    int sx0 = swzq(cx0), sx1 = swzq(cx1);

                    if (gz >= (float)(OS - 1)) {   // both z-corners clamp to 127
                        float wy0 = 1.0f - ffy, wy1 = ffy;
                        float wx0 = 1.0f - ffx, wx1 = ffx;
                        float v_s = v * S_FIX;
                        float m_s = m * S_FIX;

                        int u0 = cy0 - ybase;
                        bool n0 = (cy0 - r <= 5) && (r - cy0 <= 5);
                        if (n0 && (unsigned)u0 < 32u) {
                            unsigned long long* row = &sh[u0 << 7];
                            float a = v_s * wy0, bb = m_s * wy0;
                            atomicAdd(&row[sx0], packt(a * wx0, bb * wx0));
                            atomicAdd(&row[sx1], packt(a * wx1, bb * wx1));
                        }
                        int u1 = cy1 - ybase;
                        bool n1 = (cy1 - r <= 5) && (r - cy1 <= 5);
                        if (n1 && (unsigned)u1 < 32u) {
                            unsigned long long* row = &sh[u1 << 7];
                            float a = v_s * wy1, bb = m_s * wy1;
                            atomicAdd(&row[sx0], packt(a * wx0, bb * wx0));
                            atomicAdd(&row[sx1], packt(a * wx1, bb * wx1));
                        }
                        if (homeRow && (!n0 || !n1)) {   // far-y (~never)
                            const int pbase = (OS - 1) << 14;
                            #pragma unroll
                            for (int e2 = 0; e2 < 2; ++e2) {
                                bool far = e2 ? !n1 : !n0;
                                if (!far) continue;
                                int cy = e2 ? cy1 : cy0;
                                float wy = e2 ? wy1 : wy0;
                                unsigned base = atomicAdd(gcnt, 2u);
                                #pragma unroll
                                for (int f2 = 0; f2 < 2; ++f2) {
                                    unsigned slt = base + f2;
                                    if (slt < LCAP) {
                                        float wgt = wy * (f2 ? wx1 : wx0);
                                        int4 qq;
                                        qq.x = pbase + (cy << 7) + (f2 ? cx1 : cx0);
                                        qq.y = __float_as_int(v * wgt);
                                        qq.z = __float_as_int(m * wgt);
                                        qq.w = 0;
                                        list[slt] = qq;
                                    }
                                }
                            }
                        }
                    } else if (homeRow) {
                        // rare boundary (z~128 with big negative flow_z): 8 records
                        float fzf = floorf(gz);
                        float ffz = gz - fzf;
                        int iz0 = (int)fzf;
                        unsigned base = atomicAdd(gcnt, 8u);
                        int t = 0;
                        #pragma unroll
                        for (int d2 = 0; d2 < 2; ++d2) {
                            int cz = min(max(iz0 + d2, 0), OS - 1);
                            float wz = d2 ? ffz : 1.0f - ffz;
                            #pragma unroll
                            for (int e2 = 0; e2 < 2; ++e2) {
                                int cy = e2 ? cy1 : cy0;
                                float wzy = wz * (e2 ? ffy : 1.0f - ffy);
                                #pragma unroll
                                for (int f2 = 0; f2 < 2; ++f2) {
                                    int cx = f2 ? cx1 : cx0;
                                    float wgt = wzy * (f2 ? ffx : 1.0f - ffx);
                                    unsigned slt = base + t;
                                    if (slt < LCAP) {
                                        int4 qq;
                                        qq.x = (cz << 14) + (cy << 7) + cx;
                                        qq.y = __float_as_int(v * wgt);
                                        qq.z = __float_as_int(m * wgt);
                                        qq.w = 0;
                                        list[slt] = qq;
                                    }
                                    ++t;
                                }
                            }
                        }
                    }
                }
            }
        }

        __syncthreads();

        // unpack + store quarter-plane partials (both channels)
        float* dst0 = partials + (size_t)g * 2 * PLANE_CELLS;
        float* dst1 = dst0 + PLANE_CELLS;
        for (int i = tid; i < 32 * OS; i += 512) {
            int row = i >> 7, c = i & 127;
            unsigned long long cell = sh[(row << 7) | swzq(c)];
            float v = (float)(int)(cell >> 32) * INV_FIX;
            float m = (float)(int)(unsigned)cell * INV_FIX;
            int o = ((ybase + row) << 7) + c;
            dst0[o] = v;
            dst1[o] = m;
        }
    }
}

// ---- K2: fused full plane reduction (64 deep) + overflow-record apply ----
#define RBLK 128    // reduction blocks: 128 x 256 = 32768 cells (2ch x 16384)
__global__ __launch_bounds__(256) void finalize(
    float* __restrict__ out, const float* __restrict__ partials,
    const unsigned* __restrict__ gcnt, const int* __restrict__ counts,
    const int4* __restrict__ regs, const int4* __restrict__ list)
{
    int b = blockIdx.x;
    if (b < RBLK) {
        int t = b * 256 + threadIdx.x;            // 0..32767
        int ch   = t >> 14;
        int cell = t & 16383;
        const float* p = partials + (size_t)ch * PLANE_CELLS + cell;
        float s = 0.0f;
        #pragma unroll 8
        for (int g = 0; g < PGROUPS; ++g)
            s += p[(size_t)g * 2 * PLANE_CELLS];
        atomAddF(out + ch * OS3 + ((OS - 1) << 14) + cell, s);
    } else if (b < RBLK + GBLK) {
        int rb = b - RBLK;
        int n = counts[rb];
        const int4* r = regs + (size_t)rb * REG_CAP;
        for (int i = threadIdx.x; i < n; i += 256) {
            int4 q = r[i];
            atomAddF(out + q.x,       __int_as_float(q.y));
            atomAddF(out + OS3 + q.x, __int_as_float(q.z));
        }
    } else {
        unsigned n = *gcnt;
        if (n > LCAP) n = LCAP;
        for (unsigned i = (unsigned)(b - RBLK - GBLK) * 256 + threadIdx.x;
             i < n; i += 8 * 256) {
            int4 q = list[i];
            atomAddF(out + q.x,       __int_as_float(q.y));
            atomAddF(out + OS3 + q.x, __int_as_float(q.z));
        }
    }
}

// ---------------- fallback (ws too small): naive merged scatter ------------
__global__ __launch_bounds__(256) void warp_push_naive(
    const float* __restrict__ x, const float* __restrict__ flow,
    const float* __restrict__ mask, float* __restrict__ out, int N)
{
    int idx = blockIdx.x * blockDim.x + threadIdx.x;
    if (idx >= N) return;
    int w = idx & 127, h = (idx >> 7) & 127, z = idx >> 14;
    float gz = flow[idx] + (float)z;
    float gy = flow[N + idx] + (float)h;
    float gx = flow[2 * N + idx] + (float)w;
    float m = mask[idx];
    float v0 = x[idx] * m;
    float fz0 = floorf(gz), fy0 = floorf(gy), fx0 = floorf(gx);
    float fz = gz - fz0, fy = gy - fy0, fx = gx - fx0;
    int iz0 = (int)fz0, iy0 = (int)fy0, ix0 = (int)fx0;
    #pragma unroll
    for (int dz = 0; dz < 2; ++dz) {
        int cz = min(max(iz0 + dz, 0), OS - 1);
        float wz = dz ? fz : 1.0f - fz;
        #pragma unroll
        for (int dy = 0; dy < 2; ++dy) {
            int cy = min(max(iy0 + dy, 0), OS - 1);
            float wzy = wz * (dy ? fy : 1.0f - fy);
            #pragma unroll
            for (int dx = 0; dx < 2; ++dx) {
                int cx = min(max(ix0 + dx, 0), OS - 1);
                float wgt = wzy * (dx ? fx : 1.0f - fx);
                int o = (cz << 14) + (cy << 7) + cx;
                atomAddF(out + o,       v0 * wgt);
                atomAddF(out + OS3 + o, m * wgt);
            }
        }
    }
}

extern "C" void kernel_launch(void* const* d_in, const int* in_sizes, int n_in,
                              void* d_out, int out_size, void* d_ws, size_t ws_size,
                              hipStream_t stream) {
    (void)in_sizes; (void)n_in; (void)out_size;
    const float* x    = (const float*)d_in[0];
    const float* flow = (const float*)d_in[1];
    const float* mask = (const float*)d_in[2];
    float* out = (float*)d_out;

    if (ws_size >= (size_t)WS_NEED) {
        char* wsb = (char*)d_ws;
        unsigned* gcnt = (unsigned*)(wsb + OFF_CNT);
        int* counts    = (int*)(wsb + OFF_COUNTS);
        int4* regs     = (int4*)(wsb + OFF_REGS);
        int4* list     = (int4*)(wsb + OFF_LIST);
        float* parts   = (float*)(wsb + OFF_PART);

        hipMemsetAsync(d_ws, 0, 64, stream);   // zero list counter

        warp_fused<<<GBLK + PBLK, 512, 0, stream>>>(
            x, flow, mask, out, parts, gcnt, counts, regs, list);
        finalize<<<RBLK + GBLK + 8, 256, 0, stream>>>(
            out, parts, gcnt, counts, regs, list);
    } else {
        hipMemsetAsync(d_out, 0, (size_t)2 * OS3 * sizeof(float), stream);
        warp_push_naive<<<NSRC / 256, 256, 0, stream>>>(x, flow, mask, out, NSRC);
    }
}

// Round 7
// 188.906 us; speedup vs baseline: 20.4310x; 20.4310x over previous
//
#include <hip/hip_runtime.h>

// WarpingLayer_3stacks: trilinear scatter-splat (grid_push) of
// intensities = [x*mask, mask] into 128^3, coords = flow + meshgrid.
// Input 384x128x128 f32. Output [1,2,128,128,128] f32.
//
// R1: global f32 atomicAdd is the wall -> privatize in LDS.
// R3-R6: structure-invariant ~187us => LDS atomic throughput is the pipe.
// R7/R8: pack both channels in one u64 (ds_add_u64, 32.18 fixed pt) -> 247.
// R9: fuse gather+plane (co-schedule pipes) -> 206; R10: TZ=8 scan-amp cut
//     -> 193, K1=74us at 1.36 cy/lane-atomic (33.5M u64 atomics).
// R11: balance roles: plane PSPB 2->4 => 512 gather + 256 plane = 768 blocks
//     = exactly 3/CU; round-robin gives every CU {2 gather + 1 plane} =
//     identical 131K lane-atomics/CU. 190.2us, K1=75.6us. ===== BEST =====
// R12 FAILED (200): 4 blocks/CU doubled partials traffic + plane overhead;
//     conditional loads serialized the pipeline. Occupancy not the limiter.
// R13 FAILED (198): per-lane apron filter useless - continue is per-lane,
//     cost is per-wave (P(any of 128 px passes) ~ 1).
// R14 FAILED (304): symmetric HALO=2 -> 0.38 records/px flood (y-driven).
// R15 FAILED (221): 2 blocks/CU latency-bound (VALUBusy 29%). Bracketed:
//     2/CU=103, 3/CU=75.6, 4/CU=87 us. 3 blocks/CU frozen.
// R16 FAILED (203): register prefetch displaced compiler schedule
//     (VALUBusy 49->41). ILP/TLP/filter/tile-size all refuted.
// R17 FAILED (3859, absmax 2.78): asymmetric NZ=1 premise WRONG - flow z
//     rescale is (384-1)/(384-1)=1.0, sigma_z=1, P(far-z)=0.32/px -> 2.7M
//     records overflowed REG_CAP+LCAP (dropped = accuracy loss) and
//     serialized on scnt/gcnt (VALUBusy 1.2%). HALO=3 is required.
// R18: byte-exact revert to R11. Six isolated experiments bracketed every
//     structural axis; R11 is the measured local optimum of this family.

#define OS    128
#define OS3   (OS * OS * OS)
#define SRC_D 384
#define SRC_H 128
#define SRC_W 128
#define NSRC  (SRC_D * SRC_H * SRC_W)
#define ZSPLIT 128
#define PLANE_CELLS (OS * OS)

// gather tiling: block owns out[z0:z0+8][y0:y0+4][0:128]
#define TZ 8
#define TY 4
#define HALO 3
#define NJOBS 140          // (TZ+6)=14 z-rows x (TY+6)=10 y-rows
#define GITER 9            // ceil(140/16)
#define GBLK  512          // 16 z-tiles x 32 y-tiles

// plane tiling: quarter-plane (32 rows) per block, 4 z-slabs per group
#define PGROUPS 64         // z-groups (4 slabs each)
#define PSPB    4
#define PBLK    (PGROUPS * 4)   // 256 plane blocks

#define REG_CAP 1024       // per-gather-block record region
#define LCAP    65536      // shared overflow list

// ws layout (bytes)
#define OFF_CNT    0
#define OFF_COUNTS 1024
#define OFF_REGS   8192
#define OFF_LIST   (OFF_REGS + GBLK * REG_CAP * 16)           //  8,396,800
#define OFF_PART   (16 * 1024 * 1024)
#define WS_NEED    (OFF_PART + PGROUPS * 2 * PLANE_CELLS * 4) // 24 MB

#define S_FIX   262144.0f            // 2^18
#define INV_FIX (1.0f / 262144.0f)

// pack prescaled (a = v*wgt*2^18, b = m*wgt*2^18) via truncating cvt.
// b >= 0 and cell sums << 2^31 so low field never carries into high field.
__device__ __forceinline__ unsigned long long packt(float a, float b) {
    int vi = (int)a;
    int mi = (int)b;
    return ((unsigned long long)(unsigned)vi << 32) | (unsigned long long)(unsigned)mi;
}

// u64-cell bank swizzle (involution): spreads stride-4 column access.
__device__ __forceinline__ int swzq(int c) { return c ^ ((c >> 4) & 7); }

__device__ __forceinline__ void atomAddF(float* p, float v) {
    unsafeAtomicAdd(p, v);
}

// =================== K1: fused gather (z<128) + plane (z>=128) =============
// grid.x = GBLK + PBLK = 768, 512 threads, 32KB LDS -> exactly 3 blocks/CU;
// round-robin dispatch => each CU holds 2 gather + 1 plane (balanced atomics).
__global__ __launch_bounds__(512) void warp_fused(
    const float* __restrict__ x, const float* __restrict__ flow,
    const float* __restrict__ mask, float* __restrict__ out,
    float* __restrict__ partials,
    unsigned* __restrict__ gcnt, int* __restrict__ counts,
    int4* __restrict__ regs, int4* __restrict__ list)
{
    __shared__ unsigned long long sh[4096];   // 32 KB
    __shared__ int scnt;

    const int tid = threadIdx.x;
    const int b = blockIdx.x;

    const float4* __restrict__ fz4 = (const float4*)flow;
    const float4* __restrict__ fy4 = (const float4*)(flow + NSRC);
    const float4* __restrict__ fx4 = (const float4*)(flow + 2 * NSRC);
    const float4* __restrict__ m4p = (const float4*)mask;
    const float4* __restrict__ x4p = (const float4*)x;

    if (b < GBLK) {
        // ---------------- gather role ----------------
        if (tid == 0) scnt = 0;
        #pragma unroll
        for (int s = 0; s < 4096 / 512; ++s)
            sh[tid + s * 512] = 0ull;
        __syncthreads();

        const int z0 = (b & 15) * TZ;
        const int y0 = (b >> 4) * TY;
        const int wq = tid & 31;
        const int slot = tid >> 5;

        for (int it = 0; it < GITER; ++it) {
            int j = it * 16 + slot;
            int dz = j / 10, dyy = j - dz * 10;
            int zzr = z0 - HALO + dz;
            int hhr = y0 - HALO + dyy;
            int zz = min(max(zzr, 0), ZSPLIT - 1);
            int hh = min(max(hhr, 0), OS - 1);
            bool vrow = (j < NJOBS) && (zzr >= 0) && (zzr < ZSPLIT) &&
                        (hhr >= 0) && (hhr < OS);
            bool home = vrow && (zzr >= z0) && (zzr < z0 + TZ) &&
                        (hhr >= y0) && (hhr < y0 + TY);

            int idx4 = (((zz << 14) + (hh << 7)) >> 2) + wq;
            float4 vfz = fz4[idx4];       // unconditional clamped-address loads
            float4 vfy = fy4[idx4];
            float4 vfx = fx4[idx4];
            float4 vm  = m4p[idx4];
            float4 vx  = x4p[idx4];

            if (!vrow) continue;

            #pragma unroll
            for (int p = 0; p < 4; ++p) {
                float gz = ((float*)&vfz)[p] + (float)zz;
                float gy = ((float*)&vfy)[p] + (float)hh;
                float fzf = floorf(gz), fyf = floorf(gy);
                float ffz = gz - fzf, ffy = gy - fyf;
                int iz0 = (int)fzf, iy0 = (int)fyf;

                int cz0 = min(max(iz0,     0), OS - 1);
                int cz1 = min(max(iz0 + 1, 0), OS - 1);
                int cy0 = min(max(iy0,     0), OS - 1);
                int cy1 = min(max(iy0 + 1, 0), OS - 1);

                bool zin = (cz1 >= z0) && (cz0 < z0 + TZ);
                bool yin = (cy1 >= y0) && (cy0 < y0 + TY);
                if (!home && !(zin && yin)) continue;

                int w = wq * 4 + p;
                float gx = ((float*)&vfx)[p] + (float)w;
                float fxf = floorf(gx);
                float ffx = gx - fxf;
                int ix0 = (int)fxf;
                int cx0 = min(max(ix0,     0), OS - 1);
                int cx1 = min(max(ix0 + 1, 0), OS - 1);

                float m = ((float*)&vm)[p];
                float v = ((float*)&vx)[p] * m;
                float v_s = v * S_FIX;      // prescaled fixed-point inputs
                float m_s = m * S_FIX;

                #pragma unroll
                for (int d2 = 0; d2 < 2; ++d2) {
                    int cz = d2 ? cz1 : cz0;
                    float wz = d2 ? ffz : 1.0f - ffz;
                    bool nz = (cz - zz <= HALO) && (zz - cz <= HALO);
                    int uz = cz - z0;
                    #pragma unroll
                    for (int e2 = 0; e2 < 2; ++e2) {
                        int cy = e2 ? cy1 : cy0;
                        float wzy = wz * (e2 ? ffy : 1.0f - ffy);
                        bool ny = (cy - hh <= HALO) && (hh - cy <= HALO);
                        int uy = cy - y0;
                        bool nearc = nz && ny;
                        #pragma unroll
                        for (int f2 = 0; f2 < 2; ++f2) {
                            int cx = f2 ? cx1 : cx0;
                            float wgt = wzy * (f2 ? ffx : 1.0f - ffx);
                            if (nearc) {
                                if ((unsigned)uz < TZ && (unsigned)uy < TY) {
                                    int off = ((uz * TY + uy) << 7) + swzq(cx);
                                    atomicAdd(&sh[off], packt(v_s * wgt, m_s * wgt));
                                }
                            } else if (home) {
                                int4 r;
                                r.x = (cz << 14) + (cy << 7) + cx;
                                r.y = __float_as_int(v * wgt);
                                r.z = __float_as_int(m * wgt);
                                r.w = 0;
                                int s = atomicAdd(&scnt, 1);
                                if (s < REG_CAP) regs[b * REG_CAP + s] = r;
                                else {
                                    unsigned g = atomicAdd(gcnt, 1u);
                                    if (g < LCAP) list[g] = r;
                                }
                            }
                        }
                    }
                }
            }
        }

        __syncthreads();
        if (tid == 0) counts[b] = min(scnt, REG_CAP);

        // unpack + plain-store owned tile (tile grid partitions the volume)
        for (int i = tid; i < TZ * TY * OS; i += 512) {
            int row = i >> 7;              // uz*TY + uy, 0..31
            int c   = i & 127;
            unsigned long long cell = sh[(row << 7) | swzq(c)];
            float v = (float)(int)(cell >> 32) * INV_FIX;
            float m = (float)(int)(unsigned)cell * INV_FIX;
            int uz = row >> 2, uy = row & 3;
            int o = ((z0 + uz) << 14) + ((y0 + uy) << 7) + c;
            out[o]       = v;
            out[OS3 + o] = m;
        }
    } else {
        // ---------------- plane role: quarter-plane, 4 z-slabs ----------------
        const int pb = b - GBLK;
        const int g  = pb >> 2;           // z-group: slabs 128+4g .. 131+4g
        const int q  = pb & 3;            // y-quarter
        const int ybase = q << 5;
        const int rlo = max(0, ybase - 5);
        const int rhi = min(OS, ybase + 32 + 5);

        #pragma unroll
        for (int s = 0; s < 4096 / 512; ++s)
            sh[tid + s * 512] = 0ull;
        __syncthreads();

        const int wq = tid & 31;
        const int rs = tid >> 5;          // 0..15

        for (int s = 0; s < PSPB; ++s) {
            int z = ZSPLIT + g * PSPB + s;
            for (int rb = 0; rb < 3; ++rb) {
                int r = rlo + rb * 16 + rs;
                bool valid = r < rhi;
                int rc = min(r, OS - 1);
                int idx4 = (((z << 14) + (rc << 7)) >> 2) + wq;
                float4 vfz = fz4[idx4];
                float4 vfy = fy4[idx4];
                float4 vfx = fx4[idx4];
                float4 vm  = m4p[idx4];
                float4 vx  = x4p[idx4];
                if (!valid) continue;
                bool homeRow = ((r >> 5) == q);

                #pragma unroll
                for (int p = 0; p < 4; ++p) {
                    int w = wq * 4 + p;
                    float gz = ((float*)&vfz)[p] + (float)z;
                    float gy = ((float*)&vfy)[p] + (float)r;
                    float gx = ((float*)&vfx)[p] + (float)w;
                    float m  = ((float*)&vm)[p];
                    float v  = ((float*)&vx)[p] * m;

                    float fyf = floorf(gy), fxf = floorf(gx);
                    float ffy = gy - fyf, ffx = gx - fxf;
                    int iy0 = (int)fyf, ix0 = (int)fxf;
                    int cy0 = min(max(iy0,     0), OS - 1);
                    int cy1 = min(max(iy0 + 1, 0), OS - 1);
                    int cx0 = min(max(ix0,     0), OS - 1);
                    int cx1 = min(max(ix0 + 1, 0), OS - 1);
                    int sx0 = swzq(cx0), sx1 = swzq(cx1);

                    if (gz >= (float)(OS - 1)) {   // both z-corners clamp to 127
                        float wy0 = 1.0f - ffy, wy1 = ffy;
                        float wx0 = 1.0f - ffx, wx1 = ffx;
                        float v_s = v * S_FIX;
                        float m_s = m * S_FIX;

                        int u0 = cy0 - ybase;
                        bool n0 = (cy0 - r <= 5) && (r - cy0 <= 5);
                        if (n0 && (unsigned)u0 < 32u) {
                            unsigned long long* row = &sh[u0 << 7];
                            float a = v_s * wy0, bb = m_s * wy0;
                            atomicAdd(&row[sx0], packt(a * wx0, bb * wx0));
                            atomicAdd(&row[sx1], packt(a * wx1, bb * wx1));
                        }
                        int u1 = cy1 - ybase;
                        bool n1 = (cy1 - r <= 5) && (r - cy1 <= 5);
                        if (n1 && (unsigned)u1 < 32u) {
                            unsigned long long* row = &sh[u1 << 7];
                            float a = v_s * wy1, bb = m_s * wy1;
                            atomicAdd(&row[sx0], packt(a * wx0, bb * wx0));
                            atomicAdd(&row[sx1], packt(a * wx1, bb * wx1));
                        }
                        if (homeRow && (!n0 || !n1)) {   // far-y (~never)
                            const int pbase = (OS - 1) << 14;
                            #pragma unroll
                            for (int e2 = 0; e2 < 2; ++e2) {
                                bool far = e2 ? !n1 : !n0;
                                if (!far) continue;
                                int cy = e2 ? cy1 : cy0;
                                float wy = e2 ? wy1 : wy0;
                                unsigned base = atomicAdd(gcnt, 2u);
                                #pragma unroll
                                for (int f2 = 0; f2 < 2; ++f2) {
                                    unsigned slt = base + f2;
                                    if (slt < LCAP) {
                                        float wgt = wy * (f2 ? wx1 : wx0);
                                        int4 qq;
                                        qq.x = pbase + (cy << 7) + (f2 ? cx1 : cx0);
                                        qq.y = __float_as_int(v * wgt);
                                        qq.z = __float_as_int(m * wgt);
                                        qq.w = 0;
                                        list[slt] = qq;
                                    }
                                }
                            }
                        }
                    } else if (homeRow) {
                        // rare boundary (z~128 with big negative flow_z): 8 records
                        float fzf = floorf(gz);
                        float ffz = gz - fzf;
                        int iz0 = (int)fzf;
                        unsigned base = atomicAdd(gcnt, 8u);
                        int t = 0;
                        #pragma unroll
                        for (int d2 = 0; d2 < 2; ++d2) {
                            int cz = min(max(iz0 + d2, 0), OS - 1);
                            float wz = d2 ? ffz : 1.0f - ffz;
                            #pragma unroll
                            for (int e2 = 0; e2 < 2; ++e2) {
                                int cy = e2 ? cy1 : cy0;
                                float wzy = wz * (e2 ? ffy : 1.0f - ffy);
                                #pragma unroll
                                for (int f2 = 0; f2 < 2; ++f2) {
                                    int cx = f2 ? cx1 : cx0;
                                    float wgt = wzy * (f2 ? ffx : 1.0f - ffx);
                                    unsigned slt = base + t;
                                    if (slt < LCAP) {
                                        int4 qq;
                                        qq.x = (cz << 14) + (cy << 7) + cx;
                                        qq.y = __float_as_int(v * wgt);
                                        qq.z = __float_as_int(m * wgt);
                                        qq.w = 0;
                                        list[slt] = qq;
                                    }
                                    ++t;
                                }
                            }
                        }
                    }
                }
            }
        }

        __syncthreads();

        // unpack + store quarter-plane partials (both channels)
        float* dst0 = partials + (size_t)g * 2 * PLANE_CELLS;
        float* dst1 = dst0 + PLANE_CELLS;
        for (int i = tid; i < 32 * OS; i += 512) {
            int row = i >> 7, c = i & 127;
            unsigned long long cell = sh[(row << 7) | swzq(c)];
            float v = (float)(int)(cell >> 32) * INV_FIX;
            float m = (float)(int)(unsigned)cell * INV_FIX;
            int o = ((ybase + row) << 7) + c;
            dst0[o] = v;
            dst1[o] = m;
        }
    }
}

// ---- K2: fused full plane reduction (64 deep) + overflow-record apply ----
#define RBLK 128    // reduction blocks: 128 x 256 = 32768 cells (2ch x 16384)
__global__ __launch_bounds__(256) void finalize(
    float* __restrict__ out, const float* __restrict__ partials,
    const unsigned* __restrict__ gcnt, const int* __restrict__ counts,
    const int4* __restrict__ regs, const int4* __restrict__ list)
{
    int b = blockIdx.x;
    if (b < RBLK) {
        int t = b * 256 + threadIdx.x;            // 0..32767
        int ch   = t >> 14;
        int cell = t & 16383;
        const float* p = partials + (size_t)ch * PLANE_CELLS + cell;
        float s = 0.0f;
        #pragma unroll 8
        for (int g = 0; g < PGROUPS; ++g)
            s += p[(size_t)g * 2 * PLANE_CELLS];
        atomAddF(out + ch * OS3 + ((OS - 1) << 14) + cell, s);
    } else if (b < RBLK + GBLK) {
        int rb = b - RBLK;
        int n = counts[rb];
        const int4* r = regs + (size_t)rb * REG_CAP;
        for (int i = threadIdx.x; i < n; i += 256) {
            int4 q = r[i];
            atomAddF(out + q.x,       __int_as_float(q.y));
            atomAddF(out + OS3 + q.x, __int_as_float(q.z));
        }
    } else {
        unsigned n = *gcnt;
        if (n > LCAP) n = LCAP;
        for (unsigned i = (unsigned)(b - RBLK - GBLK) * 256 + threadIdx.x;
             i < n; i += 8 * 256) {
            int4 q = list[i];
            atomAddF(out + q.x,       __int_as_float(q.y));
            atomAddF(out + OS3 + q.x, __int_as_float(q.z));
        }
    }
}

// ---------------- fallback (ws too small): naive merged scatter ------------
__global__ __launch_bounds__(256) void warp_push_naive(
    const float* __restrict__ x, const float* __restrict__ flow,
    const float* __restrict__ mask, float* __restrict__ out, int N)
{
    int idx = blockIdx.x * blockDim.x + threadIdx.x;
    if (idx >= N) return;
    int w = idx & 127, h = (idx >> 7) & 127, z = idx >> 14;
    float gz = flow[idx] + (float)z;
    float gy = flow[N + idx] + (float)h;
    float gx = flow[2 * N + idx] + (float)w;
    float m = mask[idx];
    float v0 = x[idx] * m;
    float fz0 = floorf(gz), fy0 = floorf(gy), fx0 = floorf(gx);
    float fz = gz - fz0, fy = gy - fy0, fx = gx - fx0;
    int iz0 = (int)fz0, iy0 = (int)fy0, ix0 = (int)fx0;
    #pragma unroll
    for (int dz = 0; dz < 2; ++dz) {
        int cz = min(max(iz0 + dz, 0), OS - 1);
        float wz = dz ? fz : 1.0f - fz;
        #pragma unroll
        for (int dy = 0; dy < 2; ++dy) {
            int cy = min(max(iy0 + dy, 0), OS - 1);
            float wzy = wz * (dy ? fy : 1.0f - fy);
            #pragma unroll
            for (int dx = 0; dx < 2; ++dx) {
                int cx = min(max(ix0 + dx, 0), OS - 1);
                float wgt = wzy * (dx ? fx : 1.0f - fx);
                int o = (cz << 14) + (cy << 7) + cx;
                atomAddF(out + o,       v0 * wgt);
                atomAddF(out + OS3 + o, m * wgt);
            }
        }
    }
}

extern "C" void kernel_launch(void* const* d_in, const int* in_sizes, int n_in,
                              void* d_out, int out_size, void* d_ws, size_t ws_size,
                              hipStream_t stream) {
    (void)in_sizes; (void)n_in; (void)out_size;
    const float* x    = (const float*)d_in[0];
    const float* flow = (const float*)d_in[1];
    const float* mask = (const float*)d_in[2];
    float* out = (float*)d_out;

    if (ws_size >= (size_t)WS_NEED) {
        char* wsb = (char*)d_ws;
        unsigned* gcnt = (unsigned*)(wsb + OFF_CNT);
        int* counts    = (int*)(wsb + OFF_COUNTS);
        int4* regs     = (int4*)(wsb + OFF_REGS);
        int4* list     = (int4*)(wsb + OFF_LIST);
        float* parts   = (float*)(wsb + OFF_PART);

        hipMemsetAsync(d_ws, 0, 64, stream);   // zero list counter

        warp_fused<<<GBLK + PBLK, 512, 0, stream>>>(
            x, flow, mask, out, parts, gcnt, counts, regs, list);
        finalize<<<RBLK + GBLK + 8, 256, 0, stream>>>(
            out, parts, gcnt, counts, regs, list);
    } else {
        hipMemsetAsync(d_out, 0, (size_t)2 * OS3 * sizeof(float), stream);
        warp_push_naive<<<NSRC / 256, 256, 0, stream>>>(x, flow, mask, out, NSRC);
    }
}